// Round 1
// baseline (797.614 us; speedup 1.0000x reference)
//
#include <hip/hip_runtime.h>

// ---------------------------------------------------------------------------
// GPT-2 attention block on MI355X (gfx950), bf16 MFMA compute.
//   qkv = x @ w_attn + b_attn ; split q,k,v ; causal softmax(q k^T / 8) v ;
//   out = attn @ w_proj + b_proj.  Outputs: out, k^T [B,H,D,S], v [B,H,S,D].
// ---------------------------------------------------------------------------

typedef __attribute__((ext_vector_type(8))) short bfx8;
typedef __attribute__((ext_vector_type(4))) short bfx4;
typedef __attribute__((ext_vector_type(4))) float fx4;

#define MFMA(a, b, c) __builtin_amdgcn_mfma_f32_16x16x32_bf16(a, b, c, 0, 0, 0)

#define S_CTX 2048
#define NE 1024
#define NH 16
#define HD 64
#define MROWS 8192  // B*S = 4*2048

__device__ __forceinline__ short f2bf(float f) {
  unsigned u = __float_as_uint(f);
  unsigned r = u + 0x7fffu + ((u >> 16) & 1u);  // round-to-nearest-even
  return (short)(r >> 16);
}

// ---------------- fp32 -> bf16 convert (vectorized) ------------------------
__global__ __launch_bounds__(256) void convert_bf16_kernel(const float* __restrict__ in,
                                                           short* __restrict__ out) {
  size_t i = (size_t)blockIdx.x * 256 + threadIdx.x;  // quad index
  fx4 v = *(const fx4*)(in + i * 4);
  bfx4 o;
#pragma unroll
  for (int j = 0; j < 4; ++j) o[j] = f2bf(v[j]);
  *(bfx4*)(out + i * 4) = o;
}

// ------------- fp32 [R][C] -> bf16 [C][R] transpose ------------------------
__global__ __launch_bounds__(256) void transpose_conv_kernel(const float* __restrict__ in,
                                                             short* __restrict__ out,
                                                             int R, int C) {
  __shared__ float tile[32][33];
  int tx = threadIdx.x, ty = threadIdx.y;
  int c0 = blockIdx.x * 32, r0 = blockIdx.y * 32;
#pragma unroll
  for (int i = 0; i < 4; ++i)
    tile[ty + i * 8][tx] = in[(size_t)(r0 + ty + i * 8) * C + c0 + tx];
  __syncthreads();
#pragma unroll
  for (int i = 0; i < 4; ++i)
    out[(size_t)(c0 + ty + i * 8) * R + r0 + tx] = f2bf(tile[tx][ty + i * 8]);
}

// ---------------- shared 128x128 bf16 GEMM mainloop ------------------------
// C[M,N] = A[M,K] @ B[N,K]^T ; 4 waves in 2x2, each wave 64x64 (4x4 mfma frags)
#define LDP 40  // padded LDS row stride (elems): 80B, 16B-aligned, conflict-free

__device__ __forceinline__ void gemm128_mainloop(const short* __restrict__ A,
                                                 const short* __restrict__ B,
                                                 const int K, const int m0, const int n0,
                                                 short* As, short* Bs, fx4 acc[4][4]) {
  const int t = threadIdx.x;
  const int lane = t & 63, w = t >> 6;
  const int g = lane >> 4, li = lane & 15;
  const int wr = w >> 1, wc = w & 1;
  for (int k0 = 0; k0 < K; k0 += 32) {
#pragma unroll
    for (int i = 0; i < 2; ++i) {
      int qq = t + 256 * i;          // 0..511 chunk id
      int row = qq >> 2;             // 0..127
      int cc = (qq & 3) * 8;         // col offset (elems)
      *(bfx8*)(As + row * LDP + cc) = *(const bfx8*)(A + (size_t)(m0 + row) * K + k0 + cc);
      *(bfx8*)(Bs + row * LDP + cc) = *(const bfx8*)(B + (size_t)(n0 + row) * K + k0 + cc);
    }
    __syncthreads();
    bfx8 af[4], bf[4];
#pragma unroll
    for (int m = 0; m < 4; ++m)
      af[m] = *(const bfx8*)(As + (wr * 64 + m * 16 + li) * LDP + g * 8);
#pragma unroll
    for (int n = 0; n < 4; ++n)
      bf[n] = *(const bfx8*)(Bs + (wc * 64 + n * 16 + li) * LDP + g * 8);
#pragma unroll
    for (int m = 0; m < 4; ++m)
#pragma unroll
      for (int n = 0; n < 4; ++n)
        acc[m][n] = MFMA(af[m], bf[n], acc[m][n]);
    __syncthreads();
  }
}

// ---------------- QKV GEMM with routing epilogue ---------------------------
// X[8192,1024] @ WT[3072,1024]^T + bias -> q(bf16,*0.125), k(bf16 + fp32 kT), v(fp32 + bf16 vT)
__global__ __launch_bounds__(256) void gemm_qkv_kernel(const short* __restrict__ X,
                                                       const short* __restrict__ WT,
                                                       const float* __restrict__ bias,
                                                       short* __restrict__ qbf,
                                                       short* __restrict__ kbf,
                                                       short* __restrict__ vT,
                                                       float* __restrict__ kT,
                                                       float* __restrict__ vout) {
  __shared__ short As[128 * LDP];
  __shared__ short Bs[128 * LDP];
  fx4 acc[4][4];
  const fx4 z = {0.f, 0.f, 0.f, 0.f};
#pragma unroll
  for (int m = 0; m < 4; ++m)
#pragma unroll
    for (int n = 0; n < 4; ++n) acc[m][n] = z;
  const int m0 = blockIdx.y * 128, n0 = blockIdx.x * 128;
  gemm128_mainloop(X, WT, 1024, m0, n0, As, Bs, acc);

  const int lane = threadIdx.x & 63, w = threadIdx.x >> 6;
  const int g = lane >> 4, li = lane & 15;
  const int wr = w >> 1, wc = w & 1;
  const int sec = n0 >> 10;  // whole 128-tile lies in one of q/k/v sections
#pragma unroll
  for (int mf = 0; mf < 4; ++mf) {
#pragma unroll
    for (int nf = 0; nf < 4; ++nf) {
      const int mrow = m0 + wr * 64 + mf * 16 + g * 4;  // + jj
      const int ncol = n0 + wc * 64 + nf * 16 + li;
      const float bv = bias[ncol];
      fx4 vv;
#pragma unroll
      for (int jj = 0; jj < 4; ++jj) vv[jj] = acc[mf][nf][jj] + bv;
      const int b = mrow >> 11, s = mrow & 2047;
      const int e = ncol & 1023, h = e >> 6, d = e & 63;
      const size_t bidx = ((size_t)((b * 16 + h) * 2048 + s)) * 64 + d;
      if (sec == 0) {
#pragma unroll
        for (int jj = 0; jj < 4; ++jj) qbf[bidx + (size_t)jj * 64] = f2bf(vv[jj] * 0.125f);
      } else if (sec == 1) {
#pragma unroll
        for (int jj = 0; jj < 4; ++jj) kbf[bidx + (size_t)jj * 64] = f2bf(vv[jj]);
        const size_t tb = ((size_t)((b * 16 + h) * 64 + d)) * 2048 + s;
        *(fx4*)(kT + tb) = vv;  // 4 consecutive s for fixed d
      } else {
#pragma unroll
        for (int jj = 0; jj < 4; ++jj) vout[bidx + (size_t)jj * 64] = vv[jj];
        const size_t tb = ((size_t)((b * 16 + h) * 64 + d)) * 2048 + s;
        bfx4 pv;
#pragma unroll
        for (int jj = 0; jj < 4; ++jj) pv[jj] = f2bf(vv[jj]);
        *(bfx4*)(vT + tb) = pv;
      }
    }
  }
}

// ---------------- output projection GEMM -----------------------------------
__global__ __launch_bounds__(256) void gemm_proj_kernel(const short* __restrict__ X,
                                                        const short* __restrict__ WT,
                                                        const float* __restrict__ bias,
                                                        float* __restrict__ out) {
  __shared__ short As[128 * LDP];
  __shared__ short Bs[128 * LDP];
  fx4 acc[4][4];
  const fx4 z = {0.f, 0.f, 0.f, 0.f};
#pragma unroll
  for (int m = 0; m < 4; ++m)
#pragma unroll
    for (int n = 0; n < 4; ++n) acc[m][n] = z;
  const int m0 = blockIdx.y * 128, n0 = blockIdx.x * 128;
  gemm128_mainloop(X, WT, 1024, m0, n0, As, Bs, acc);

  const int lane = threadIdx.x & 63, w = threadIdx.x >> 6;
  const int g = lane >> 4, li = lane & 15;
  const int wr = w >> 1, wc = w & 1;
#pragma unroll
  for (int mf = 0; mf < 4; ++mf) {
#pragma unroll
    for (int nf = 0; nf < 4; ++nf) {
      const int mrow = m0 + wr * 64 + mf * 16 + g * 4;
      const int ncol = n0 + wc * 64 + nf * 16 + li;
      const float bv = bias[ncol];
#pragma unroll
      for (int jj = 0; jj < 4; ++jj)
        out[(size_t)(mrow + jj) * 1024 + ncol] = acc[mf][nf][jj] + bv;
    }
  }
}

// ---------------- causal flash attention -----------------------------------
// Swapped QK^T: S^T = mfma(K_frag, Q_frag)  => lane holds q = lane&15,
// keys = g*4+jj (per 16-key tile).  PV consumes P in its natural register
// order by loading V (stored [D][S]) with the matching key permutation.
__global__ __launch_bounds__(256) void attn_kernel(const short* __restrict__ Q,
                                                   const short* __restrict__ Kc,
                                                   const short* __restrict__ VT,
                                                   short* __restrict__ O) {
  const int bh = blockIdx.x >> 5;    // 32 q-blocks of 64 per head
  const int qblk = blockIdx.x & 31;
  const int w = threadIdx.x >> 6;
  const int lane = threadIdx.x & 63;
  const int g = lane >> 4, li = lane & 15;
  const int q0 = qblk * 64 + w * 16;
  const size_t hoff = (size_t)bh * (S_CTX * HD);
  const short* Qh = Q + hoff;
  const short* Kh = Kc + hoff;
  const short* Vh = VT + hoff;  // [HD][S]

  const bfx8 qf0 = *(const bfx8*)(Qh + (size_t)(q0 + li) * HD + g * 8);
  const bfx8 qf1 = *(const bfx8*)(Qh + (size_t)(q0 + li) * HD + 32 + g * 8);

  fx4 acc[4];
  const fx4 z = {0.f, 0.f, 0.f, 0.f};
#pragma unroll
  for (int i = 0; i < 4; ++i) acc[i] = z;
  float m_run = -1e30f, l_run = 0.f;

  const int kmax = q0 + 15;  // inclusive causal limit of this wave's rows
  for (int k0 = 0; k0 <= kmax; k0 += 32) {
    const bfx8 kf00 = *(const bfx8*)(Kh + (size_t)(k0 + li) * HD + g * 8);
    const bfx8 kf01 = *(const bfx8*)(Kh + (size_t)(k0 + li) * HD + 32 + g * 8);
    const bfx8 kf10 = *(const bfx8*)(Kh + (size_t)(k0 + 16 + li) * HD + g * 8);
    const bfx8 kf11 = *(const bfx8*)(Kh + (size_t)(k0 + 16 + li) * HD + 32 + g * 8);
    fx4 s0 = z, s1 = z;
    s0 = MFMA(kf00, qf0, s0);
    s0 = MFMA(kf01, qf1, s0);
    s1 = MFMA(kf10, qf0, s1);
    s1 = MFMA(kf11, qf1, s1);
    if (k0 + 31 > q0) {  // partial block: apply causal mask per element
      const int qg = q0 + li;
#pragma unroll
      for (int jj = 0; jj < 4; ++jj) {
        if (k0 + g * 4 + jj > qg) s0[jj] = -1e30f;
        if (k0 + 16 + g * 4 + jj > qg) s1[jj] = -1e30f;
      }
    }
    // online softmax for row q = li (4 replicas across g; reduce over g)
    float pm = fmaxf(fmaxf(fmaxf(s0[0], s0[1]), fmaxf(s0[2], s0[3])),
                     fmaxf(fmaxf(s1[0], s1[1]), fmaxf(s1[2], s1[3])));
    pm = fmaxf(pm, __shfl_xor(pm, 16));
    pm = fmaxf(pm, __shfl_xor(pm, 32));
    const float mn = fmaxf(m_run, pm);
    const float rf = __expf(m_run - mn);
    float p0[4], p1[4];
    float ls = 0.f;
#pragma unroll
    for (int jj = 0; jj < 4; ++jj) {
      p0[jj] = __expf(s0[jj] - mn);
      p1[jj] = __expf(s1[jj] - mn);
      ls += p0[jj] + p1[jj];
    }
    ls += __shfl_xor(ls, 16);
    ls += __shfl_xor(ls, 32);
    l_run = l_run * rf + ls;
    m_run = mn;
    // redistribute rescale factor to accumulator row layout (row = g*4+jj)
    fx4 rfv;
#pragma unroll
    for (int jj = 0; jj < 4; ++jj) rfv[jj] = __shfl(rf, g * 4 + jj);
#pragma unroll
    for (int dt = 0; dt < 4; ++dt) acc[dt] *= rfv;
    // P fragment in natural register order (keys: t*16 + g*4 + jj)
    bfx8 pA;
#pragma unroll
    for (int jj = 0; jj < 4; ++jj) {
      pA[jj] = f2bf(p0[jj]);
      pA[jj + 4] = f2bf(p1[jj]);
    }
    // PV: V loaded with the SAME key permutation so reg slots line up
#pragma unroll
    for (int dt = 0; dt < 4; ++dt) {
      const short* vr = Vh + (size_t)(dt * 16 + li) * S_CTX + k0;
      const bfx4 v0 = *(const bfx4*)(vr + g * 4);
      const bfx4 v1 = *(const bfx4*)(vr + 16 + g * 4);
      bfx8 vf;
#pragma unroll
      for (int jj = 0; jj < 4; ++jj) {
        vf[jj] = v0[jj];
        vf[jj + 4] = v1[jj];
      }
      acc[dt] = MFMA(pA, vf, acc[dt]);
    }
  }
  // epilogue: divide by l (per accumulator row), merge heads
  fx4 lv;
#pragma unroll
  for (int jj = 0; jj < 4; ++jj) lv[jj] = 1.0f / __shfl(l_run, g * 4 + jj);
  const int b = bh >> 4, h = bh & 15;
#pragma unroll
  for (int dt = 0; dt < 4; ++dt)
#pragma unroll
    for (int jj = 0; jj < 4; ++jj) {
      const int s = q0 + g * 4 + jj;
      O[((size_t)(b * S_CTX + s)) * NE + h * HD + dt * 16 + li] = f2bf(acc[dt][jj] * lv[jj]);
    }
}

// ---------------------------------------------------------------------------
extern "C" void kernel_launch(void* const* d_in, const int* in_sizes, int n_in,
                              void* d_out, int out_size, void* d_ws, size_t ws_size,
                              hipStream_t stream) {
  const float* hs = (const float*)d_in[0];      // [4,2048,1024]
  const float* w_attn = (const float*)d_in[1];  // [1024,3072]
  const float* b_attn = (const float*)d_in[2];  // [3072]
  const float* w_proj = (const float*)d_in[3];  // [1024,1024]
  const float* b_proj = (const float*)d_in[4];  // [1024]

  float* out = (float*)d_out;            // [4,2048,1024]
  float* kT_out = out + 8388608;         // [4,16,64,2048]
  float* v_out = out + 2 * 8388608;      // [4,16,2048,64]

  char* ws = (char*)d_ws;
  // layout chosen so tail-overreads (none expected) never leave d_ws
  short* xbf = (short*)ws;                      // 16 MiB: x bf16, reused as attn out
  short* waT = (short*)(ws + 16777216);         //  6 MiB: w_attn^T bf16 [3072][1024]
  short* vTb = (short*)(ws + 23068672);         // 16 MiB: V^T bf16 [B,H,D,S]
  short* qbf = (short*)(ws + 39845888);         // 16 MiB: Q bf16 (pre-scaled 1/8)
  short* kbf = (short*)(ws + 56623104);         // 16 MiB: K bf16
  short* wpT = (short*)(ws + 73400320);         //  2 MiB: w_proj^T bf16

  convert_bf16_kernel<<<8192, 256, 0, stream>>>(hs, xbf);
  transpose_conv_kernel<<<dim3(96, 32), dim3(32, 8), 0, stream>>>(w_attn, waT, 1024, 3072);
  transpose_conv_kernel<<<dim3(32, 32), dim3(32, 8), 0, stream>>>(w_proj, wpT, 1024, 1024);
  gemm_qkv_kernel<<<dim3(24, 64), 256, 0, stream>>>(xbf, waT, b_attn, qbf, kbf, vTb,
                                                    kT_out, v_out);
  attn_kernel<<<2048, 256, 0, stream>>>(qbf, kbf, vTb, xbf /* attn out, reuses x buf */);
  gemm_proj_kernel<<<dim3(8, 64), 256, 0, stream>>>(xbf, wpT, b_proj, out);
}

// Round 2
// 239.833 us; speedup vs baseline: 3.3257x; 3.3257x over previous
//
#include <hip/hip_runtime.h>

// ---------------------------------------------------------------------------
// GPT-2 attention block on MI355X (gfx950), bf16 MFMA compute.
//   qkv = x @ w_attn + b_attn ; split q,k,v ; causal softmax(q k^T / 8) v ;
//   out = attn @ w_proj + b_proj.  Outputs: out, k^T [B,H,D,S], v [B,H,S,D].
// Round 2: attention rebuilt with LDS-staged K/V tiles (XOR-swizzled),
// 256-row q blocks, balanced causal pairing.
// ---------------------------------------------------------------------------

typedef __attribute__((ext_vector_type(8))) short bfx8;
typedef __attribute__((ext_vector_type(4))) short bfx4;
typedef __attribute__((ext_vector_type(4))) float fx4;

#define MFMA(a, b, c) __builtin_amdgcn_mfma_f32_16x16x32_bf16(a, b, c, 0, 0, 0)

#define S_CTX 2048
#define NE 1024
#define NH 16
#define HD 64

__device__ __forceinline__ short f2bf(float f) {
  unsigned u = __float_as_uint(f);
  unsigned r = u + 0x7fffu + ((u >> 16) & 1u);  // round-to-nearest-even
  return (short)(r >> 16);
}

// ---------------- fp32 -> bf16 convert (vectorized) ------------------------
__global__ __launch_bounds__(256) void convert_bf16_kernel(const float* __restrict__ in,
                                                           short* __restrict__ out) {
  size_t i = (size_t)blockIdx.x * 256 + threadIdx.x;  // quad index
  fx4 v = *(const fx4*)(in + i * 4);
  bfx4 o;
#pragma unroll
  for (int j = 0; j < 4; ++j) o[j] = f2bf(v[j]);
  *(bfx4*)(out + i * 4) = o;
}

// ------------- fp32 [R][C] -> bf16 [C][R] transpose ------------------------
__global__ __launch_bounds__(256) void transpose_conv_kernel(const float* __restrict__ in,
                                                             short* __restrict__ out,
                                                             int R, int C) {
  __shared__ float tile[32][33];
  int tx = threadIdx.x, ty = threadIdx.y;
  int c0 = blockIdx.x * 32, r0 = blockIdx.y * 32;
#pragma unroll
  for (int i = 0; i < 4; ++i)
    tile[ty + i * 8][tx] = in[(size_t)(r0 + ty + i * 8) * C + c0 + tx];
  __syncthreads();
#pragma unroll
  for (int i = 0; i < 4; ++i)
    out[(size_t)(c0 + ty + i * 8) * R + r0 + tx] = f2bf(tile[tx][ty + i * 8]);
}

// ---------------- shared 128x128 bf16 GEMM mainloop ------------------------
// C[M,N] = A[M,K] @ B[N,K]^T ; 4 waves in 2x2, each wave 64x64 (4x4 mfma frags)
#define LDP 40  // padded LDS row stride (elems): 80B, 16B-aligned, conflict-free

__device__ __forceinline__ void gemm128_mainloop(const short* __restrict__ A,
                                                 const short* __restrict__ B,
                                                 const int K, const int m0, const int n0,
                                                 short* As, short* Bs, fx4 acc[4][4]) {
  const int t = threadIdx.x;
  const int lane = t & 63, w = t >> 6;
  const int g = lane >> 4, li = lane & 15;
  const int wr = w >> 1, wc = w & 1;
  for (int k0 = 0; k0 < K; k0 += 32) {
#pragma unroll
    for (int i = 0; i < 2; ++i) {
      int qq = t + 256 * i;          // 0..511 chunk id
      int row = qq >> 2;             // 0..127
      int cc = (qq & 3) * 8;         // col offset (elems)
      *(bfx8*)(As + row * LDP + cc) = *(const bfx8*)(A + (size_t)(m0 + row) * K + k0 + cc);
      *(bfx8*)(Bs + row * LDP + cc) = *(const bfx8*)(B + (size_t)(n0 + row) * K + k0 + cc);
    }
    __syncthreads();
    bfx8 af[4], bf[4];
#pragma unroll
    for (int m = 0; m < 4; ++m)
      af[m] = *(const bfx8*)(As + (wr * 64 + m * 16 + li) * LDP + g * 8);
#pragma unroll
    for (int n = 0; n < 4; ++n)
      bf[n] = *(const bfx8*)(Bs + (wc * 64 + n * 16 + li) * LDP + g * 8);
#pragma unroll
    for (int m = 0; m < 4; ++m)
#pragma unroll
      for (int n = 0; n < 4; ++n)
        acc[m][n] = MFMA(af[m], bf[n], acc[m][n]);
    __syncthreads();
  }
}

// ---------------- QKV GEMM with routing epilogue ---------------------------
__global__ __launch_bounds__(256) void gemm_qkv_kernel(const short* __restrict__ X,
                                                       const short* __restrict__ WT,
                                                       const float* __restrict__ bias,
                                                       short* __restrict__ qbf,
                                                       short* __restrict__ kbf,
                                                       short* __restrict__ vT,
                                                       float* __restrict__ kT,
                                                       float* __restrict__ vout) {
  __shared__ short As[128 * LDP];
  __shared__ short Bs[128 * LDP];
  fx4 acc[4][4];
  const fx4 z = {0.f, 0.f, 0.f, 0.f};
#pragma unroll
  for (int m = 0; m < 4; ++m)
#pragma unroll
    for (int n = 0; n < 4; ++n) acc[m][n] = z;
  const int m0 = blockIdx.y * 128, n0 = blockIdx.x * 128;
  gemm128_mainloop(X, WT, 1024, m0, n0, As, Bs, acc);

  const int lane = threadIdx.x & 63, w = threadIdx.x >> 6;
  const int g = lane >> 4, li = lane & 15;
  const int wr = w >> 1, wc = w & 1;
  const int sec = n0 >> 10;  // whole 128-tile lies in one of q/k/v sections
#pragma unroll
  for (int mf = 0; mf < 4; ++mf) {
#pragma unroll
    for (int nf = 0; nf < 4; ++nf) {
      const int mrow = m0 + wr * 64 + mf * 16 + g * 4;  // + jj
      const int ncol = n0 + wc * 64 + nf * 16 + li;
      const float bv = bias[ncol];
      fx4 vv;
#pragma unroll
      for (int jj = 0; jj < 4; ++jj) vv[jj] = acc[mf][nf][jj] + bv;
      const int b = mrow >> 11, s = mrow & 2047;
      const int e = ncol & 1023, h = e >> 6, d = e & 63;
      const size_t bidx = ((size_t)((b * 16 + h) * 2048 + s)) * 64 + d;
      if (sec == 0) {
#pragma unroll
        for (int jj = 0; jj < 4; ++jj) qbf[bidx + (size_t)jj * 64] = f2bf(vv[jj] * 0.125f);
      } else if (sec == 1) {
#pragma unroll
        for (int jj = 0; jj < 4; ++jj) kbf[bidx + (size_t)jj * 64] = f2bf(vv[jj]);
        const size_t tb = ((size_t)((b * 16 + h) * 64 + d)) * 2048 + s;
        *(fx4*)(kT + tb) = vv;  // 4 consecutive s for fixed d
      } else {
#pragma unroll
        for (int jj = 0; jj < 4; ++jj) vout[bidx + (size_t)jj * 64] = vv[jj];
        const size_t tb = ((size_t)((b * 16 + h) * 64 + d)) * 2048 + s;
        bfx4 pv;
#pragma unroll
        for (int jj = 0; jj < 4; ++jj) pv[jj] = f2bf(vv[jj]);
        *(bfx4*)(vT + tb) = pv;
      }
    }
  }
}

// ---------------- output projection GEMM -----------------------------------
__global__ __launch_bounds__(256) void gemm_proj_kernel(const short* __restrict__ X,
                                                        const short* __restrict__ WT,
                                                        const float* __restrict__ bias,
                                                        float* __restrict__ out) {
  __shared__ short As[128 * LDP];
  __shared__ short Bs[128 * LDP];
  fx4 acc[4][4];
  const fx4 z = {0.f, 0.f, 0.f, 0.f};
#pragma unroll
  for (int m = 0; m < 4; ++m)
#pragma unroll
    for (int n = 0; n < 4; ++n) acc[m][n] = z;
  const int m0 = blockIdx.y * 128, n0 = blockIdx.x * 128;
  gemm128_mainloop(X, WT, 1024, m0, n0, As, Bs, acc);

  const int lane = threadIdx.x & 63, w = threadIdx.x >> 6;
  const int g = lane >> 4, li = lane & 15;
  const int wr = w >> 1, wc = w & 1;
#pragma unroll
  for (int mf = 0; mf < 4; ++mf) {
#pragma unroll
    for (int nf = 0; nf < 4; ++nf) {
      const int mrow = m0 + wr * 64 + mf * 16 + g * 4;
      const int ncol = n0 + wc * 64 + nf * 16 + li;
      const float bv = bias[ncol];
#pragma unroll
      for (int jj = 0; jj < 4; ++jj)
        out[(size_t)(mrow + jj) * 1024 + ncol] = acc[mf][nf][jj] + bv;
    }
  }
}

// ---------------- causal flash attention (LDS-staged) ----------------------
// Block: one head, 256 q rows. 4 waves x 64 rows (4 m-frags of 16).
// Swapped QK^T: S^T = mfma(K, Q) => lane holds q = lane&15, keys = g*4+jj.
// K tile [64 keys][64 d] and V^T tile [64 d][64 keys] staged in LDS with
// byte ^= (row&7)<<4 XOR swizzle (bank-conflict-free reads).
#define KSW(base, row, byte) ((char*)(base) + (row) * 128 + ((byte) ^ (((row) & 7) << 4)))

__global__ __launch_bounds__(256, 2) void attn_kernel(const short* __restrict__ Q,
                                                      const short* __restrict__ Kc,
                                                      const short* __restrict__ VT,
                                                      short* __restrict__ O) {
  __shared__ short Ks[64 * 64];
  __shared__ short Vs[64 * 64];

  const int bh = blockIdx.x & 63;
  const int qc_rev = blockIdx.x >> 6;
  const int qchunk = (qc_rev < 4) ? (7 - qc_rev) : (qc_rev - 4);  // balanced pairs
  const int q0 = qchunk * 256;

  const int t = threadIdx.x;
  const int w = t >> 6;
  const int lane = t & 63;
  const int g = lane >> 4, li = lane & 15;

  const size_t hoff = (size_t)bh * (S_CTX * HD);
  const short* Qh = Q + hoff;
  const short* Kh = Kc + hoff;
  const short* Vh = VT + hoff;  // [HD][S]

  // Q fragments: 4 m-frags x 2 halves (d 0-31 / 32-63)
  bfx8 qf[4][2];
#pragma unroll
  for (int mf = 0; mf < 4; ++mf) {
    const int qm = q0 + w * 64 + mf * 16;
    qf[mf][0] = *(const bfx8*)(Qh + (size_t)(qm + li) * HD + g * 8);
    qf[mf][1] = *(const bfx8*)(Qh + (size_t)(qm + li) * HD + 32 + g * 8);
  }

  fx4 acc[4][4];
  const fx4 z = {0.f, 0.f, 0.f, 0.f};
#pragma unroll
  for (int mf = 0; mf < 4; ++mf)
#pragma unroll
    for (int dt = 0; dt < 4; ++dt) acc[mf][dt] = z;
  float m_run[4] = {-1e30f, -1e30f, -1e30f, -1e30f};
  float l_run[4] = {0.f, 0.f, 0.f, 0.f};

  const int r = t >> 3;        // staging row 0..31
  const int c16 = t & 7;       // 16B unit within 128B row
  const int qlim = q0 + w * 64 + 63;   // this wave's inclusive causal limit
  const int kmax = q0 + 255;

  for (int k0 = 0; k0 <= kmax; k0 += 64) {
    // ---- stage K[64][64] and V^T[64][64] tiles (reg-staged, swizzled) ----
    const bfx8 kreg0 = *(const bfx8*)(Kh + (size_t)(k0 + r) * HD + c16 * 8);
    const bfx8 kreg1 = *(const bfx8*)(Kh + (size_t)(k0 + r + 32) * HD + c16 * 8);
    const bfx8 vreg0 = *(const bfx8*)(Vh + (size_t)r * S_CTX + k0 + c16 * 8);
    const bfx8 vreg1 = *(const bfx8*)(Vh + (size_t)(r + 32) * S_CTX + k0 + c16 * 8);
    __syncthreads();  // previous tile fully consumed
    *(bfx8*)KSW(Ks, r, c16 * 16) = kreg0;
    *(bfx8*)KSW(Ks, r + 32, c16 * 16) = kreg1;
    *(bfx8*)KSW(Vs, r, c16 * 16) = vreg0;
    *(bfx8*)KSW(Vs, r + 32, c16 * 16) = vreg1;
    __syncthreads();

    if (k0 > qlim) continue;  // wave fully past its causal region (still barriers)

    // ---- K fragments: kt (16-key tiles) x half (d) ----
    bfx8 kf[4][2];
#pragma unroll
    for (int kt = 0; kt < 4; ++kt) {
#pragma unroll
      for (int h = 0; h < 2; ++h)
        kf[kt][h] = *(const bfx8*)KSW(Ks, kt * 16 + li, h * 64 + g * 16);
    }
    // ---- V fragments: dt (d cols) x kc (32-key chunk), key-permuted ----
    bfx8 vf[4][2];
#pragma unroll
    for (int dt = 0; dt < 4; ++dt) {
#pragma unroll
      for (int kc = 0; kc < 2; ++kc) {
        const int row = dt * 16 + li;
        const bfx4 a = *(const bfx4*)KSW(Vs, row, kc * 64 + g * 8);
        const bfx4 b = *(const bfx4*)KSW(Vs, row, kc * 64 + 32 + g * 8);
        bfx8 vv;
#pragma unroll
        for (int j = 0; j < 4; ++j) {
          vv[j] = a[j];
          vv[j + 4] = b[j];
        }
        vf[dt][kc] = vv;
      }
    }

#pragma unroll
    for (int mf = 0; mf < 4; ++mf) {
      const int qm = q0 + w * 64 + mf * 16;
      if (k0 > qm + 15) continue;  // frag fully masked (wave-uniform)
      fx4 st[4];
#pragma unroll
      for (int kt = 0; kt < 4; ++kt) {
        st[kt] = z;
        st[kt] = MFMA(kf[kt][0], qf[mf][0], st[kt]);
        st[kt] = MFMA(kf[kt][1], qf[mf][1], st[kt]);
      }
      if (k0 + 63 > qm) {  // diagonal tile: causal mask per element
        const int qg = qm + li;
#pragma unroll
        for (int kt = 0; kt < 4; ++kt)
#pragma unroll
          for (int jj = 0; jj < 4; ++jj)
            if (k0 + kt * 16 + g * 4 + jj > qg) st[kt][jj] = -1e30f;
      }
      // ---- online softmax for q row = li ----
      float pm = st[0][0];
#pragma unroll
      for (int kt = 0; kt < 4; ++kt)
#pragma unroll
        for (int jj = 0; jj < 4; ++jj) pm = fmaxf(pm, st[kt][jj]);
      pm = fmaxf(pm, __shfl_xor(pm, 16));
      pm = fmaxf(pm, __shfl_xor(pm, 32));
      const float mn = fmaxf(m_run[mf], pm);
      const float rf = __expf(m_run[mf] - mn);
      float p[16];
      float ls = 0.f;
#pragma unroll
      for (int kt = 0; kt < 4; ++kt)
#pragma unroll
        for (int jj = 0; jj < 4; ++jj) {
          p[kt * 4 + jj] = __expf(st[kt][jj] - mn);
          ls += p[kt * 4 + jj];
        }
      ls += __shfl_xor(ls, 16);
      ls += __shfl_xor(ls, 32);
      l_run[mf] = l_run[mf] * rf + ls;
      m_run[mf] = mn;
      fx4 rfv;
#pragma unroll
      for (int jj = 0; jj < 4; ++jj) rfv[jj] = __shfl(rf, g * 4 + jj);
#pragma unroll
      for (int dt = 0; dt < 4; ++dt) acc[mf][dt] *= rfv;
      // ---- P fragments (key-slot order matches vf) ----
      bfx8 pA0, pA1;
#pragma unroll
      for (int jj = 0; jj < 4; ++jj) {
        pA0[jj] = f2bf(p[0 * 4 + jj]);
        pA0[jj + 4] = f2bf(p[1 * 4 + jj]);
        pA1[jj] = f2bf(p[2 * 4 + jj]);
        pA1[jj + 4] = f2bf(p[3 * 4 + jj]);
      }
#pragma unroll
      for (int dt = 0; dt < 4; ++dt) {
        acc[mf][dt] = MFMA(pA0, vf[dt][0], acc[mf][dt]);
        acc[mf][dt] = MFMA(pA1, vf[dt][1], acc[mf][dt]);
      }
    }
  }

  // ---- epilogue: divide by l, merge heads ----
  const int b = bh >> 4, h = bh & 15;
#pragma unroll
  for (int mf = 0; mf < 4; ++mf) {
    const int qm = q0 + w * 64 + mf * 16;
    fx4 lv;
#pragma unroll
    for (int jj = 0; jj < 4; ++jj) lv[jj] = 1.0f / __shfl(l_run[mf], g * 4 + jj);
#pragma unroll
    for (int dt = 0; dt < 4; ++dt)
#pragma unroll
      for (int jj = 0; jj < 4; ++jj) {
        const int s = qm + g * 4 + jj;
        O[((size_t)(b * S_CTX + s)) * NE + h * HD + dt * 16 + li] =
            f2bf(acc[mf][dt][jj] * lv[jj]);
      }
  }
}

// ---------------------------------------------------------------------------
extern "C" void kernel_launch(void* const* d_in, const int* in_sizes, int n_in,
                              void* d_out, int out_size, void* d_ws, size_t ws_size,
                              hipStream_t stream) {
  const float* hs = (const float*)d_in[0];      // [4,2048,1024]
  const float* w_attn = (const float*)d_in[1];  // [1024,3072]
  const float* b_attn = (const float*)d_in[2];  // [3072]
  const float* w_proj = (const float*)d_in[3];  // [1024,1024]
  const float* b_proj = (const float*)d_in[4];  // [1024]

  float* out = (float*)d_out;            // [4,2048,1024]
  float* kT_out = out + 8388608;         // [4,16,64,2048]
  float* v_out = out + 2 * 8388608;      // [4,16,2048,64]

  char* ws = (char*)d_ws;
  short* xbf = (short*)ws;                      // 16 MiB: x bf16, reused as attn out
  short* waT = (short*)(ws + 16777216);         //  6 MiB: w_attn^T bf16 [3072][1024]
  short* vTb = (short*)(ws + 23068672);         // 16 MiB: V^T bf16 [B,H,D,S]
  short* qbf = (short*)(ws + 39845888);         // 16 MiB: Q bf16 (pre-scaled 1/8)
  short* kbf = (short*)(ws + 56623104);         // 16 MiB: K bf16
  short* wpT = (short*)(ws + 73400320);         //  2 MiB: w_proj^T bf16

  convert_bf16_kernel<<<8192, 256, 0, stream>>>(hs, xbf);
  transpose_conv_kernel<<<dim3(96, 32), dim3(32, 8), 0, stream>>>(w_attn, waT, 1024, 3072);
  transpose_conv_kernel<<<dim3(32, 32), dim3(32, 8), 0, stream>>>(w_proj, wpT, 1024, 1024);
  gemm_qkv_kernel<<<dim3(24, 64), 256, 0, stream>>>(xbf, waT, b_attn, qbf, kbf, vTb,
                                                    kT_out, v_out);
  attn_kernel<<<512, 256, 0, stream>>>(qbf, kbf, vTb, xbf /* attn out */);
  gemm_proj_kernel<<<dim3(8, 64), 256, 0, stream>>>(xbf, wpT, b_proj, out);
}